// Round 10
// baseline (146.868 us; speedup 1.0000x reference)
//
#include <hip/hip_runtime.h>

typedef short bf16x8 __attribute__((ext_vector_type(8)));
typedef float f32x4  __attribute__((ext_vector_type(4)));

#define BIG_F 1e10f
constexpr int B = 16;
constexpr int N = 4096;
constexpr int ROWS = 256;        // rows (x-points) per block
constexpr int COLS = 256;        // cols (y-points) per block
constexpr int NRB = N / ROWS;    // 16
constexpr int NCB = N / COLS;    // 16
constexpr int NCC = COLS / 32;   // 8 column double-chunks per block

// truncating bf16 hi/lo split: v ~= hi + lo with |v-hi-lo| <= 2^-16 |v|
__device__ __forceinline__ void split(float v, unsigned short& h, unsigned short& l) {
    unsigned hb = __float_as_uint(v) & 0xFFFF0000u;
    h = (unsigned short)(hb >> 16);
    float r = v - __uint_as_float(hb);
    l = (unsigned short)(__float_as_uint(r) >> 16);
}

__device__ __forceinline__ float min3f(float a, float b, float c) {
    return fminf(fminf(a, b), c);
}
__device__ __forceinline__ float min4f(f32x4 c) {
    return fminf(fminf(c[0], c[1]), fminf(c[2], c[3]));
}

// P[n,m] = xx[n] + yy[m] - 2 x_n . y_m (+BIG on masked rows/cols) via
// mfma_f32_16x16x32_bf16 with hi/lo bf16 splits (layouts verified in R9):
//   A_k(n) = [ah0..2, ah0..2, al0..2, al0..2, xxh, xxl, 1, 1]
//   B_k(m) = [yh0..2, yl0..2, yh0..2, yl0..2, 1, 1, yyh, yyl]
__global__ __launch_bounds__(256) void chamfer_mfma(
    const float* __restrict__ x, const float* __restrict__ y,
    const int* __restrict__ mask,
    float* __restrict__ rowpart,   // [B][NCB][N] exclusive slots (no init)
    float* __restrict__ colpart,   // [B][NRB][N]
    float* __restrict__ out)
{
    const int rb = blockIdx.x & 15;   // row-block
    const int cb = blockIdx.x >> 4;   // col-block
    const int b  = blockIdx.y;
    const int t  = threadIdx.x;

    __shared__ unsigned short Apack[ROWS * 16];  // 8 KB
    __shared__ unsigned short Bpack[COLS * 16];  // 8 KB
    __shared__ float colbuf[4][COLS];            // 4 KB

    if (blockIdx.x == 0 && b == 0 && t == 0) out[0] = 0.0f;  // finalize = next dispatch

    const unsigned short one = 0x3F80;  // bf16 1.0

    // ---- pack A: 256 x-points, one per thread ----
    {
        int n = rb * ROWS + t;
        const float* xb = x + (size_t)b * 3 * N;
        float x0 = xb[n], x1 = xb[N + n], x2 = xb[2 * N + n];
        float madd = mask[b * N + n] ? 0.0f : BIG_F;
        float xx = fmaf(x2, x2, fmaf(x1, x1, x0 * x0)) + madd;
        unsigned short ah0, al0, ah1, al1, ah2, al2, xh, xl;
        split(-2.0f * x0, ah0, al0);
        split(-2.0f * x1, ah1, al1);
        split(-2.0f * x2, ah2, al2);
        split(xx, xh, xl);
        unsigned short* p = &Apack[t * 16];
        p[0] = ah0; p[1] = ah1; p[2] = ah2; p[3] = ah0; p[4] = ah1; p[5] = ah2;
        p[6] = al0; p[7] = al1; p[8] = al2; p[9] = al0; p[10] = al1; p[11] = al2;
        p[12] = xh; p[13] = xl; p[14] = one; p[15] = one;
    }
    // ---- pack B: 256 y-points, one per thread ----
    {
        int m = cb * COLS + t;
        const float* yb = y + (size_t)b * 3 * N;
        float y0 = yb[m], y1 = yb[N + m], y2 = yb[2 * N + m];
        float madd = mask[b * N + m] ? 0.0f : BIG_F;
        float yy = fmaf(y2, y2, fmaf(y1, y1, y0 * y0)) + madd;
        unsigned short yh0, yl0, yh1, yl1, yh2, yl2, qh, ql;
        split(y0, yh0, yl0);
        split(y1, yh1, yl1);
        split(y2, yh2, yl2);
        split(yy, qh, ql);
        unsigned short* p = &Bpack[t * 16];
        p[0] = yh0; p[1] = yh1; p[2] = yh2; p[3] = yl0; p[4] = yl1; p[5] = yl2;
        p[6] = yh0; p[7] = yh1; p[8] = yh2; p[9] = yl0; p[10] = yl1; p[11] = yl2;
        p[12] = one; p[13] = one; p[14] = qh; p[15] = ql;
    }
    __syncthreads();

    const int w  = t >> 6;    // wave 0..3 (rows w*64..w*64+63)
    const int L  = t & 63;
    const int lq = L >> 4;    // quad
    const int lc = L & 15;

    const bf16x8 zero8 = {0, 0, 0, 0, 0, 0, 0, 0};
    const f32x4  zf4   = {0.f, 0.f, 0.f, 0.f};

    bf16x8 afr[4];
#pragma unroll
    for (int s = 0; s < 4; ++s) {
        afr[s] = zero8;
        if (lq < 2)
            afr[s] = *(const bf16x8*)&Apack[(w * 64 + s * 16 + lc) * 16 + lq * 8];
    }

    float rm[4][4];
#pragma unroll
    for (int s = 0; s < 4; ++s)
#pragma unroll
        for (int r = 0; r < 4; ++r) rm[s][r] = 1e30f;

    // software pipeline: B-frags for chunk cc+1 load while chunk cc reduces
    bf16x8 nbf0 = zero8, nbf1 = zero8;
    if (lq < 2) {
        nbf0 = *(const bf16x8*)&Bpack[lc * 16 + lq * 8];
        nbf1 = *(const bf16x8*)&Bpack[(lc + 16) * 16 + lq * 8];
    }

#pragma unroll
    for (int cc = 0; cc < NCC; ++cc) {
        bf16x8 bf0 = nbf0, bf1 = nbf1;
        if (cc + 1 < NCC && lq < 2) {
            int c0 = (cc + 1) * 32 + lc;
            nbf0 = *(const bf16x8*)&Bpack[c0 * 16 + lq * 8];
            nbf1 = *(const bf16x8*)&Bpack[(c0 + 16) * 16 + lq * 8];
        }
        f32x4 C0[4], C1[4];
#pragma unroll
        for (int s = 0; s < 4; ++s) {
            C0[s] = __builtin_amdgcn_mfma_f32_16x16x32_bf16(afr[s], bf0, zf4, 0, 0, 0);
            C1[s] = __builtin_amdgcn_mfma_f32_16x16x32_bf16(afr[s], bf1, zf4, 0, 0, 0);
        }
        // col-mins for this chunk's 32 cols (min over wave's 64 rows)
        float v0 = fminf(fminf(min4f(C0[0]), min4f(C0[1])),
                         fminf(min4f(C0[2]), min4f(C0[3])));
        float v1 = fminf(fminf(min4f(C1[0]), min4f(C1[1])),
                         fminf(min4f(C1[2]), min4f(C1[3])));
        // row-mins accumulate in regs
#pragma unroll
        for (int s = 0; s < 4; ++s)
#pragma unroll
            for (int r = 0; r < 4; ++r)
                rm[s][r] = min3f(rm[s][r], C0[s][r], C1[s][r]);
        v0 = fminf(v0, __shfl_xor(v0, 16));
        v0 = fminf(v0, __shfl_xor(v0, 32));
        v1 = fminf(v1, __shfl_xor(v1, 16));
        v1 = fminf(v1, __shfl_xor(v1, 32));
        if (lq == 0) {
            colbuf[w][cc * 32 + lc] = v0;
            colbuf[w][cc * 32 + 16 + lc] = v1;
        }
    }

    // finish row-mins: reduce across the 16 col-lanes
#pragma unroll
    for (int off = 1; off <= 8; off <<= 1)
#pragma unroll
        for (int s = 0; s < 4; ++s)
#pragma unroll
            for (int r = 0; r < 4; ++r)
                rm[s][r] = fminf(rm[s][r], __shfl_xor(rm[s][r], off));
    if (lc == 0) {
        float* rp = rowpart + ((size_t)b * NCB + cb) * N + rb * ROWS + w * 64;
#pragma unroll
        for (int s = 0; s < 4; ++s)
#pragma unroll
            for (int r = 0; r < 4; ++r)
                rp[s * 16 + lq * 4 + r] = rm[s][r];
    }

    __syncthreads();
    // combine 4 waves' col-mins -> block's col partial (min over 256 rows)
    {
        int c = t;
        float v = fminf(fminf(colbuf[0][c], colbuf[1][c]),
                        fminf(colbuf[2][c], colbuf[3][c]));
        colpart[((size_t)b * NRB + rb) * N + cb * COLS + c] = v;
    }
}

__global__ __launch_bounds__(256) void finalize_kernel(
    const int* __restrict__ mask,
    const float* __restrict__ rowpart, const float* __restrict__ colpart,
    float* __restrict__ out)
{
    const int b   = blockIdx.x & 15;
    const int dir = (blockIdx.x >> 4) & 1;
    const int q   = blockIdx.x >> 5;   // quarter 0..3
    const int t   = threadIdx.x;
    const int* mrow = mask + b * N;

    int cnt = 0;
    for (int i = t; i < N / 4; i += 256) {
        int4 mk = ((const int4*)mrow)[i];
        cnt += mk.x + mk.y + mk.z + mk.w;
    }

    const float* base = (dir ? colpart : rowpart) + (size_t)b * 16 * N;

    const int p0 = q * 1024 + t * 4;
    float4 mn = *(const float4*)(base + p0);
#pragma unroll
    for (int pb = 1; pb < 16; ++pb) {
        float4 v = *(const float4*)(base + (size_t)pb * N + p0);
        mn.x = fminf(mn.x, v.x); mn.y = fminf(mn.y, v.y);
        mn.z = fminf(mn.z, v.z); mn.w = fminf(mn.w, v.w);
    }
    int4 mk = *(const int4*)(mrow + p0);
    float s = (mk.x ? mn.x : 0.f) + (mk.y ? mn.y : 0.f)
            + (mk.z ? mn.z : 0.f) + (mk.w ? mn.w : 0.f);

    for (int off = 32; off > 0; off >>= 1) {
        s   += __shfl_down(s, off);
        cnt += __shfl_down(cnt, off);
    }
    __shared__ float rs[4];
    __shared__ int   rc[4];
    const int wv = t >> 6;
    if ((t & 63) == 0) { rs[wv] = s; rc[wv] = cnt; }
    __syncthreads();
    if (t == 0) {
        float S = rs[0] + rs[1] + rs[2] + rs[3];
        float C = (float)(rc[0] + rc[1] + rc[2] + rc[3]);
        atomicAdd(out, (S / C) * (1.0f / 16.0f));
    }
}

extern "C" void kernel_launch(void* const* d_in, const int* in_sizes, int n_in,
                              void* d_out, int out_size, void* d_ws, size_t ws_size,
                              hipStream_t stream) {
    const float* x    = (const float*)d_in[0];
    const float* y    = (const float*)d_in[1];
    const int*   mask = (const int*)d_in[2];

    float* rowpart = (float*)d_ws;                    // B*NCB*N floats = 4 MB
    float* colpart = rowpart + (size_t)B * NCB * N;   // B*NRB*N floats = 4 MB

    chamfer_mfma<<<dim3(NRB * NCB, B), 256, 0, stream>>>(
        x, y, mask, rowpart, colpart, (float*)d_out);
    finalize_kernel<<<dim3(128), 256, 0, stream>>>(
        mask, rowpart, colpart, (float*)d_out);
}

// Round 11
// 140.033 us; speedup vs baseline: 1.0488x; 1.0488x over previous
//
#include <hip/hip_runtime.h>

typedef short bf16x8 __attribute__((ext_vector_type(8)));
typedef float f32x4  __attribute__((ext_vector_type(4)));

#define BIG_F 1e10f
constexpr int B = 16;
constexpr int N = 4096;
constexpr int ROWS = 256;        // rows (x-points) per block
constexpr int COLS = 256;        // cols (y-points) per block
constexpr int NRB = N / ROWS;    // 16
constexpr int NCB = N / COLS;    // 16
constexpr int NCC = COLS / 32;   // 8 column double-chunks per block
constexpr int AST = 24;          // pack stride in shorts (48B: breaks bank pattern)
constexpr int CBS = 264;         // colbuf row stride floats (264%32=8 -> 2-way max)

// truncating bf16 hi/lo split: v ~= hi + lo with |v-hi-lo| <= 2^-16 |v|
__device__ __forceinline__ void split(float v, unsigned short& h, unsigned short& l) {
    unsigned hb = __float_as_uint(v) & 0xFFFF0000u;
    h = (unsigned short)(hb >> 16);
    float r = v - __uint_as_float(hb);
    l = (unsigned short)(__float_as_uint(r) >> 16);
}

__device__ __forceinline__ float min3f(float a, float b, float c) {
    return fminf(fminf(a, b), c);
}
__device__ __forceinline__ float min4f(f32x4 c) {
    return fminf(fminf(c[0], c[1]), fminf(c[2], c[3]));
}

// P[n,m] = xx[n] + yy[m] - 2 x_n . y_m (+BIG on masked rows/cols) via
// mfma_f32_16x16x32_bf16 with hi/lo bf16 splits (layouts verified R9):
//   A_k(n) = [ah0..2, ah0..2, al0..2, al0..2, xxh, xxl, 1, 1]
//   B_k(m) = [yh0..2, yl0..2, yh0..2, yl0..2, 1, 1, yyh, yyl]
__global__ __launch_bounds__(256) void chamfer_mfma(
    const float* __restrict__ x, const float* __restrict__ y,
    const int* __restrict__ mask,
    float* __restrict__ rowpart,   // [B][NCB][N] exclusive slots (no init)
    float* __restrict__ colpart,   // [B][NRB][N]
    float* __restrict__ out)
{
    const int rb = blockIdx.x & 15;   // row-block
    const int cb = blockIdx.x >> 4;   // col-block
    const int b  = blockIdx.y;
    const int t  = threadIdx.x;

    __shared__ unsigned short Apack[ROWS * AST];  // 12 KB
    __shared__ unsigned short Bpack[COLS * AST];  // 12 KB
    __shared__ float colbuf[16][CBS];             // 16.5 KB (row = wave*4+quad)

    if (blockIdx.x == 0 && b == 0 && t == 0) out[0] = 0.0f;  // finalize = next dispatch

    const unsigned short one = 0x3F80;  // bf16 1.0

    // ---- pack A: 256 x-points, one per thread ----
    {
        int n = rb * ROWS + t;
        const float* xb = x + (size_t)b * 3 * N;
        float x0 = xb[n], x1 = xb[N + n], x2 = xb[2 * N + n];
        float madd = mask[b * N + n] ? 0.0f : BIG_F;
        float xx = fmaf(x2, x2, fmaf(x1, x1, x0 * x0)) + madd;
        unsigned short ah0, al0, ah1, al1, ah2, al2, xh, xl;
        split(-2.0f * x0, ah0, al0);
        split(-2.0f * x1, ah1, al1);
        split(-2.0f * x2, ah2, al2);
        split(xx, xh, xl);
        unsigned short* p = &Apack[t * AST];
        p[0] = ah0; p[1] = ah1; p[2] = ah2; p[3] = ah0; p[4] = ah1; p[5] = ah2;
        p[6] = al0; p[7] = al1; p[8] = al2; p[9] = al0; p[10] = al1; p[11] = al2;
        p[12] = xh; p[13] = xl; p[14] = one; p[15] = one;
    }
    // ---- pack B: 256 y-points, one per thread ----
    {
        int m = cb * COLS + t;
        const float* yb = y + (size_t)b * 3 * N;
        float y0 = yb[m], y1 = yb[N + m], y2 = yb[2 * N + m];
        float madd = mask[b * N + m] ? 0.0f : BIG_F;
        float yy = fmaf(y2, y2, fmaf(y1, y1, y0 * y0)) + madd;
        unsigned short yh0, yl0, yh1, yl1, yh2, yl2, qh, ql;
        split(y0, yh0, yl0);
        split(y1, yh1, yl1);
        split(y2, yh2, yl2);
        split(yy, qh, ql);
        unsigned short* p = &Bpack[t * AST];
        p[0] = yh0; p[1] = yh1; p[2] = yh2; p[3] = yl0; p[4] = yl1; p[5] = yl2;
        p[6] = yh0; p[7] = yh1; p[8] = yh2; p[9] = yl0; p[10] = yl1; p[11] = yl2;
        p[12] = one; p[13] = one; p[14] = qh; p[15] = ql;
    }
    __syncthreads();

    const int w  = t >> 6;    // wave 0..3 (rows w*64..w*64+63)
    const int L  = t & 63;
    const int lq = L >> 4;    // quad
    const int lc = L & 15;

    const bf16x8 zero8 = {0, 0, 0, 0, 0, 0, 0, 0};
    const f32x4  zf4   = {0.f, 0.f, 0.f, 0.f};

    bf16x8 afr[4];
#pragma unroll
    for (int s = 0; s < 4; ++s) {
        afr[s] = zero8;
        if (lq < 2)
            afr[s] = *(const bf16x8*)&Apack[(w * 64 + s * 16 + lc) * AST + lq * 8];
    }

    float rm[4][4];
#pragma unroll
    for (int s = 0; s < 4; ++s)
#pragma unroll
        for (int r = 0; r < 4; ++r) rm[s][r] = 1e30f;

    for (int cc = 0; cc < NCC; ++cc) {
        const int c0 = cc * 32 + lc;
        bf16x8 bf0 = zero8, bf1 = zero8;
        if (lq < 2) {
            bf0 = *(const bf16x8*)&Bpack[c0 * AST + lq * 8];
            bf1 = *(const bf16x8*)&Bpack[(c0 + 16) * AST + lq * 8];
        }
        f32x4 C0[4], C1[4];
#pragma unroll
        for (int s = 0; s < 4; ++s) {
            C0[s] = __builtin_amdgcn_mfma_f32_16x16x32_bf16(afr[s], bf0, zf4, 0, 0, 0);
            C1[s] = __builtin_amdgcn_mfma_f32_16x16x32_bf16(afr[s], bf1, zf4, 0, 0, 0);
        }
        // row-mins accumulate in regs (v_min3)
#pragma unroll
        for (int s = 0; s < 4; ++s)
#pragma unroll
            for (int r = 0; r < 4; ++r)
                rm[s][r] = min3f(rm[s][r], C0[s][r], C1[s][r]);
        // per-quad col-min partials -> LDS (NO cross-lane shuffle in the loop)
        float v0 = fminf(fminf(min4f(C0[0]), min4f(C0[1])),
                         fminf(min4f(C0[2]), min4f(C0[3])));
        float v1 = fminf(fminf(min4f(C1[0]), min4f(C1[1])),
                         fminf(min4f(C1[2]), min4f(C1[3])));
        colbuf[w * 4 + lq][cc * 32 + lc] = v0;
        colbuf[w * 4 + lq][cc * 32 + 16 + lc] = v1;
    }

    // finish row-mins: reduce across the 16 col-lanes
#pragma unroll
    for (int off = 1; off <= 8; off <<= 1)
#pragma unroll
        for (int s = 0; s < 4; ++s)
#pragma unroll
            for (int r = 0; r < 4; ++r)
                rm[s][r] = fminf(rm[s][r], __shfl_xor(rm[s][r], off));
    if (lc == 0) {
        float* rp = rowpart + ((size_t)b * NCB + cb) * N + rb * ROWS + w * 64;
#pragma unroll
        for (int s = 0; s < 4; ++s)
#pragma unroll
            for (int r = 0; r < 4; ++r)
                rp[s * 16 + lq * 4 + r] = rm[s][r];
    }

    __syncthreads();
    // combine 16 quad-partials -> block's col partial (min over 256 rows)
    {
        int c = t;
        float v = colbuf[0][c];
#pragma unroll
        for (int q = 1; q < 16; ++q) v = fminf(v, colbuf[q][c]);
        colpart[((size_t)b * NRB + rb) * N + cb * COLS + c] = v;
    }
}

__global__ __launch_bounds__(256) void finalize_kernel(
    const int* __restrict__ mask,
    const float* __restrict__ rowpart, const float* __restrict__ colpart,
    float* __restrict__ out)
{
    const int b   = blockIdx.x & 15;
    const int dir = (blockIdx.x >> 4) & 1;
    const int q   = blockIdx.x >> 5;   // quarter 0..3
    const int t   = threadIdx.x;
    const int* mrow = mask + b * N;

    int cnt = 0;
    for (int i = t; i < N / 4; i += 256) {
        int4 mk = ((const int4*)mrow)[i];
        cnt += mk.x + mk.y + mk.z + mk.w;
    }

    const float* base = (dir ? colpart : rowpart) + (size_t)b * 16 * N;

    const int p0 = q * 1024 + t * 4;
    float4 mn = *(const float4*)(base + p0);
#pragma unroll
    for (int pb = 1; pb < 16; ++pb) {
        float4 v = *(const float4*)(base + (size_t)pb * N + p0);
        mn.x = fminf(mn.x, v.x); mn.y = fminf(mn.y, v.y);
        mn.z = fminf(mn.z, v.z); mn.w = fminf(mn.w, v.w);
    }
    int4 mk = *(const int4*)(mrow + p0);
    float s = (mk.x ? mn.x : 0.f) + (mk.y ? mn.y : 0.f)
            + (mk.z ? mn.z : 0.f) + (mk.w ? mn.w : 0.f);

    for (int off = 32; off > 0; off >>= 1) {
        s   += __shfl_down(s, off);
        cnt += __shfl_down(cnt, off);
    }
    __shared__ float rs[4];
    __shared__ int   rc[4];
    const int wv = t >> 6;
    if ((t & 63) == 0) { rs[wv] = s; rc[wv] = cnt; }
    __syncthreads();
    if (t == 0) {
        float S = rs[0] + rs[1] + rs[2] + rs[3];
        float C = (float)(rc[0] + rc[1] + rc[2] + rc[3]);
        atomicAdd(out, (S / C) * (1.0f / 16.0f));
    }
}

extern "C" void kernel_launch(void* const* d_in, const int* in_sizes, int n_in,
                              void* d_out, int out_size, void* d_ws, size_t ws_size,
                              hipStream_t stream) {
    const float* x    = (const float*)d_in[0];
    const float* y    = (const float*)d_in[1];
    const int*   mask = (const int*)d_in[2];

    float* rowpart = (float*)d_ws;                    // B*NCB*N floats = 4 MB
    float* colpart = rowpart + (size_t)B * NCB * N;   // B*NRB*N floats = 4 MB

    chamfer_mfma<<<dim3(NRB * NCB, B), 256, 0, stream>>>(
        x, y, mask, rowpart, colpart, (float*)d_out);
    finalize_kernel<<<dim3(128), 256, 0, stream>>>(
        mask, rowpart, colpart, (float*)d_out);
}

// Round 12
// 99.474 us; speedup vs baseline: 1.4765x; 1.4077x over previous
//
#include <hip/hip_runtime.h>

typedef short bf16x8 __attribute__((ext_vector_type(8)));
typedef float f32x4  __attribute__((ext_vector_type(4)));

#define BIG_F 1e10f
constexpr int B = 16;
constexpr int N = 4096;
constexpr int ROWS = 256;        // rows (x-points) per block
constexpr int COLS = 512;        // cols (y-points) per block
constexpr int NRB = N / ROWS;    // 16
constexpr int NCB = N / COLS;    // 8
constexpr int NCC = COLS / 32;   // 16 column double-chunks per block

// truncating bf16 hi/lo split: v ~= hi + lo with |v-hi-lo| <= 2^-16 |v|
__device__ __forceinline__ void split(float v, unsigned short& h, unsigned short& l) {
    unsigned hb = __float_as_uint(v) & 0xFFFF0000u;
    h = (unsigned short)(hb >> 16);
    float r = v - __uint_as_float(hb);
    l = (unsigned short)(__float_as_uint(r) >> 16);
}

__device__ __forceinline__ float min3f(float a, float b, float c) {
    return fminf(fminf(a, b), c);
}
__device__ __forceinline__ float min4f(f32x4 c) {
    return fminf(fminf(c[0], c[1]), fminf(c[2], c[3]));
}

// P[n,m] = xx[n] + yy[m] - 2 x_n . y_m (+BIG on masked rows/cols) via
// mfma_f32_16x16x32_bf16 with hi/lo bf16 splits (layouts verified R9):
//   A_k(n) = [ah0..2, ah0..2, al0..2, al0..2, xxh, xxl, 1, 1]
//   B_k(m) = [yh0..2, yl0..2, yh0..2, yl0..2, 1, 1, yyh, yyl]
__global__ __launch_bounds__(256) void chamfer_mfma(
    const float* __restrict__ x, const float* __restrict__ y,
    const int* __restrict__ mask,
    float* __restrict__ rowpart,   // [B][NCB][N] exclusive slots (no init)
    float* __restrict__ colpart,   // [B][NRB][N]
    float* __restrict__ out)
{
    const int rb = blockIdx.x & 15;   // row-block
    const int cb = blockIdx.x >> 4;   // col-block
    const int b  = blockIdx.y;
    const int t  = threadIdx.x;

    __shared__ unsigned short Apack[ROWS * 16];  // 8 KB
    __shared__ unsigned short Bpack[COLS * 16];  // 16 KB
    __shared__ float colbuf[4][COLS];            // 8 KB

    if (blockIdx.x == 0 && b == 0 && t == 0) out[0] = 0.0f;  // finalize = next dispatch

    const unsigned short one = 0x3F80;  // bf16 1.0

    // ---- pack A: 256 x-points, one per thread ----
    {
        int n = rb * ROWS + t;
        const float* xb = x + (size_t)b * 3 * N;
        float x0 = xb[n], x1 = xb[N + n], x2 = xb[2 * N + n];
        float madd = mask[b * N + n] ? 0.0f : BIG_F;
        float xx = fmaf(x2, x2, fmaf(x1, x1, x0 * x0)) + madd;
        unsigned short ah0, al0, ah1, al1, ah2, al2, xh, xl;
        split(-2.0f * x0, ah0, al0);
        split(-2.0f * x1, ah1, al1);
        split(-2.0f * x2, ah2, al2);
        split(xx, xh, xl);
        unsigned short* p = &Apack[t * 16];
        p[0] = ah0; p[1] = ah1; p[2] = ah2; p[3] = ah0; p[4] = ah1; p[5] = ah2;
        p[6] = al0; p[7] = al1; p[8] = al2; p[9] = al0; p[10] = al1; p[11] = al2;
        p[12] = xh; p[13] = xl; p[14] = one; p[15] = one;
    }
    // ---- pack B: 512 y-points, two per thread ----
#pragma unroll
    for (int i = 0; i < 2; ++i) {
        int c = t + i * 256;
        int m = cb * COLS + c;
        const float* yb = y + (size_t)b * 3 * N;
        float y0 = yb[m], y1 = yb[N + m], y2 = yb[2 * N + m];
        float madd = mask[b * N + m] ? 0.0f : BIG_F;
        unsigned short yh0, yl0, yh1, yl1, yh2, yl2, qh, ql;
        float yy = fmaf(y2, y2, fmaf(y1, y1, y0 * y0)) + madd;
        split(y0, yh0, yl0);
        split(y1, yh1, yl1);
        split(y2, yh2, yl2);
        split(yy, qh, ql);
        unsigned short* p = &Bpack[c * 16];
        p[0] = yh0; p[1] = yh1; p[2] = yh2; p[3] = yl0; p[4] = yl1; p[5] = yl2;
        p[6] = yh0; p[7] = yh1; p[8] = yh2; p[9] = yl0; p[10] = yl1; p[11] = yl2;
        p[12] = one; p[13] = one; p[14] = qh; p[15] = ql;
    }
    __syncthreads();

    const int w  = t >> 6;    // wave 0..3 (rows w*64..w*64+63)
    const int L  = t & 63;
    const int lq = L >> 4;    // quad
    const int lc = L & 15;

    const bf16x8 zero8 = {0, 0, 0, 0, 0, 0, 0, 0};
    const f32x4  zf4   = {0.f, 0.f, 0.f, 0.f};

    bf16x8 afr[4];
#pragma unroll
    for (int s = 0; s < 4; ++s) {
        afr[s] = zero8;
        if (lq < 2)
            afr[s] = *(const bf16x8*)&Apack[(w * 64 + s * 16 + lc) * 16 + lq * 8];
    }

    float rm[4][4];
#pragma unroll
    for (int s = 0; s < 4; ++s)
#pragma unroll
        for (int r = 0; r < 4; ++r) rm[s][r] = 1e30f;

    // software pipeline: B-frags for chunk cc+1 load while chunk cc reduces
    bf16x8 nbf0 = zero8, nbf1 = zero8;
    if (lq < 2) {
        nbf0 = *(const bf16x8*)&Bpack[lc * 16 + lq * 8];
        nbf1 = *(const bf16x8*)&Bpack[(lc + 16) * 16 + lq * 8];
    }

    for (int cc = 0; cc < NCC; ++cc) {
        bf16x8 bf0 = nbf0, bf1 = nbf1;
        if (cc + 1 < NCC && lq < 2) {
            int c0 = (cc + 1) * 32 + lc;
            nbf0 = *(const bf16x8*)&Bpack[c0 * 16 + lq * 8];
            nbf1 = *(const bf16x8*)&Bpack[(c0 + 16) * 16 + lq * 8];
        }
        f32x4 C0[4], C1[4];
#pragma unroll
        for (int s = 0; s < 4; ++s) {
            C0[s] = __builtin_amdgcn_mfma_f32_16x16x32_bf16(afr[s], bf0, zf4, 0, 0, 0);
            C1[s] = __builtin_amdgcn_mfma_f32_16x16x32_bf16(afr[s], bf1, zf4, 0, 0, 0);
        }
        // col-mins for this chunk's 32 cols (min over wave's 64 rows)
        float v0 = fminf(fminf(min4f(C0[0]), min4f(C0[1])),
                         fminf(min4f(C0[2]), min4f(C0[3])));
        float v1 = fminf(fminf(min4f(C1[0]), min4f(C1[1])),
                         fminf(min4f(C1[2]), min4f(C1[3])));
        // row-mins accumulate in regs
#pragma unroll
        for (int s = 0; s < 4; ++s)
#pragma unroll
            for (int r = 0; r < 4; ++r)
                rm[s][r] = min3f(rm[s][r], C0[s][r], C1[s][r]);
        // cross-quad min: 3 INDEPENDENT shuffles (1 shuffle-latency deep,
        // vs 2 serial xor-16/xor-32 — the R9 chain)
        float a0 = __shfl_xor(v0, 16), b0 = __shfl_xor(v0, 32), c0s = __shfl_xor(v0, 48);
        float a1 = __shfl_xor(v1, 16), b1 = __shfl_xor(v1, 32), c1s = __shfl_xor(v1, 48);
        v0 = fminf(fminf(v0, a0), fminf(b0, c0s));
        v1 = fminf(fminf(v1, a1), fminf(b1, c1s));
        if (lq == 0) {
            colbuf[w][cc * 32 + lc] = v0;
            colbuf[w][cc * 32 + 16 + lc] = v1;
        }
    }

    // finish row-mins: reduce across the 16 col-lanes
#pragma unroll
    for (int off = 1; off <= 8; off <<= 1)
#pragma unroll
        for (int s = 0; s < 4; ++s)
#pragma unroll
            for (int r = 0; r < 4; ++r)
                rm[s][r] = fminf(rm[s][r], __shfl_xor(rm[s][r], off));
    if (lc == 0) {
        float* rp = rowpart + ((size_t)b * NCB + cb) * N + rb * ROWS + w * 64;
#pragma unroll
        for (int s = 0; s < 4; ++s)
#pragma unroll
            for (int r = 0; r < 4; ++r)
                rp[s * 16 + lq * 4 + r] = rm[s][r];
    }

    __syncthreads();
    // combine 4 waves' col-mins -> block's col partial (min over 256 rows)
    for (int c = t; c < COLS; c += 256) {
        float v = fminf(fminf(colbuf[0][c], colbuf[1][c]),
                        fminf(colbuf[2][c], colbuf[3][c]));
        colpart[((size_t)b * NRB + rb) * N + cb * COLS + c] = v;
    }
}

__global__ __launch_bounds__(256) void finalize_kernel(
    const int* __restrict__ mask,
    const float* __restrict__ rowpart, const float* __restrict__ colpart,
    float* __restrict__ out)
{
    const int b   = blockIdx.x & 15;
    const int dir = (blockIdx.x >> 4) & 1;
    const int q   = blockIdx.x >> 5;   // quarter 0..3
    const int t   = threadIdx.x;
    const int* mrow = mask + b * N;

    int cnt = 0;
    for (int i = t; i < N / 4; i += 256) {
        int4 mk = ((const int4*)mrow)[i];
        cnt += mk.x + mk.y + mk.z + mk.w;
    }

    const float* base = dir ? (colpart + (size_t)b * NRB * N)
                            : (rowpart + (size_t)b * NCB * N);
    const int npb = dir ? NRB : NCB;

    const int p0 = q * 1024 + t * 4;
    float4 mn = *(const float4*)(base + p0);
    for (int pb = 1; pb < npb; ++pb) {
        float4 v = *(const float4*)(base + (size_t)pb * N + p0);
        mn.x = fminf(mn.x, v.x); mn.y = fminf(mn.y, v.y);
        mn.z = fminf(mn.z, v.z); mn.w = fminf(mn.w, v.w);
    }
    int4 mk = *(const int4*)(mrow + p0);
    float s = (mk.x ? mn.x : 0.f) + (mk.y ? mn.y : 0.f)
            + (mk.z ? mn.z : 0.f) + (mk.w ? mn.w : 0.f);

    for (int off = 32; off > 0; off >>= 1) {
        s   += __shfl_down(s, off);
        cnt += __shfl_down(cnt, off);
    }
    __shared__ float rs[4];
    __shared__ int   rc[4];
    const int wv = t >> 6;
    if ((t & 63) == 0) { rs[wv] = s; rc[wv] = cnt; }
    __syncthreads();
    if (t == 0) {
        float S = rs[0] + rs[1] + rs[2] + rs[3];
        float C = (float)(rc[0] + rc[1] + rc[2] + rc[3]);
        atomicAdd(out, (S / C) * (1.0f / 16.0f));
    }
}

extern "C" void kernel_launch(void* const* d_in, const int* in_sizes, int n_in,
                              void* d_out, int out_size, void* d_ws, size_t ws_size,
                              hipStream_t stream) {
    const float* x    = (const float*)d_in[0];
    const float* y    = (const float*)d_in[1];
    const int*   mask = (const int*)d_in[2];

    float* rowpart = (float*)d_ws;                    // B*NCB*N floats = 2 MB
    float* colpart = rowpart + (size_t)B * NCB * N;   // B*NRB*N floats = 4 MB

    chamfer_mfma<<<dim3(NRB * NCB, B), 256, 0, stream>>>(
        x, y, mask, rowpart, colpart, (float*)d_out);
    finalize_kernel<<<dim3(128), 256, 0, stream>>>(
        mask, rowpart, colpart, (float*)d_out);
}